// Round 11
// baseline (460.607 us; speedup 1.0000x reference)
//
#include <hip/hip_runtime.h>

typedef __bf16 bf16;
typedef __attribute__((ext_vector_type(8))) __bf16 bf16x8;
typedef __attribute__((ext_vector_type(4))) __bf16 bf16x4;
typedef __attribute__((ext_vector_type(4))) float f32x4;

#define MFMA16(a, b, c) __builtin_amdgcn_mfma_f32_16x16x32_bf16((a), (b), (c), 0, 0, 0)

__device__ __forceinline__ void gload16(const void* g, void* lds) {
  __builtin_amdgcn_global_load_lds(
      (__attribute__((address_space(1))) unsigned int*)(unsigned long long)g,
      (__attribute__((address_space(3))) unsigned int*)lds, 16, 0, 0);
}

// ---------------- cast X (fp32 -> bf16) ----------------
__global__ void __launch_bounds__(256) cast_x_kernel(const float* __restrict__ X,
                                                     bf16* __restrict__ Xb) {
  int i = (blockIdx.x * 256 + threadIdx.x) * 4;
  f32x4 v = *(const f32x4*)(X + i);
  bf16x4 o;
  o[0] = (bf16)v[0]; o[1] = (bf16)v[1]; o[2] = (bf16)v[2]; o[3] = (bf16)v[3];
  *(bf16x4*)(Xb + i) = o;
}

// ---------------- transpose + cast 3 weights in one launch: WT[n][k] = W[k][n] ----------------
__global__ void __launch_bounds__(256) transpose_w3_kernel(const float* __restrict__ Wq,
                                                           const float* __restrict__ Wk,
                                                           const float* __restrict__ Wv,
                                                           bf16* __restrict__ T0,
                                                           bf16* __restrict__ T1,
                                                           bf16* __restrict__ T2) {
  __shared__ float tile[64][65];
  int which = blockIdx.x >> 10;
  int bid = blockIdx.x & 1023;
  const float* W = which == 0 ? Wq : (which == 1 ? Wk : Wv);
  bf16* WT = which == 0 ? T0 : (which == 1 ? T1 : T2);
  int n0 = (bid & 31) * 64;
  int k0 = (bid >> 5) * 64;
  int tid = threadIdx.x;
  int r = tid >> 4;
  int c4 = (tid & 15) * 4;
#pragma unroll
  for (int i = 0; i < 4; ++i) {
    f32x4 v = *(const f32x4*)(W + (size_t)(k0 + r + i * 16) * 2048 + n0 + c4);
    tile[r + i * 16][c4 + 0] = v[0];
    tile[r + i * 16][c4 + 1] = v[1];
    tile[r + i * 16][c4 + 2] = v[2];
    tile[r + i * 16][c4 + 3] = v[3];
  }
  __syncthreads();
#pragma unroll
  for (int i = 0; i < 4; ++i) {
    int n = r + i * 16;
    bf16x4 o;
    o[0] = (bf16)tile[c4 + 0][n];
    o[1] = (bf16)tile[c4 + 1][n];
    o[2] = (bf16)tile[c4 + 2][n];
    o[3] = (bf16)tile[c4 + 3][n];
    *(bf16x4*)(WT + (size_t)(n0 + n) * 2048 + k0 + c4) = o;
  }
}

__global__ void __launch_bounds__(256) transpose_w_kernel(const float* __restrict__ W,
                                                          bf16* __restrict__ WT) {
  __shared__ float tile[64][65];
  int n0 = (blockIdx.x & 31) * 64;
  int k0 = (blockIdx.x >> 5) * 64;
  int tid = threadIdx.x;
  int r = tid >> 4;
  int c4 = (tid & 15) * 4;
#pragma unroll
  for (int i = 0; i < 4; ++i) {
    f32x4 v = *(const f32x4*)(W + (size_t)(k0 + r + i * 16) * 2048 + n0 + c4);
    tile[r + i * 16][c4 + 0] = v[0];
    tile[r + i * 16][c4 + 1] = v[1];
    tile[r + i * 16][c4 + 2] = v[2];
    tile[r + i * 16][c4 + 3] = v[3];
  }
  __syncthreads();
#pragma unroll
  for (int i = 0; i < 4; ++i) {
    int n = r + i * 16;
    bf16x4 o;
    o[0] = (bf16)tile[c4 + 0][n];
    o[1] = (bf16)tile[c4 + 1][n];
    o[2] = (bf16)tile[c4 + 2][n];
    o[3] = (bf16)tile[c4 + 3][n];
    *(bf16x4*)(WT + (size_t)(n0 + n) * 2048 + k0 + c4) = o;
  }
}

// ---------------- 256x256 GEMM core: m201 8-phase schedule, 16x16 frags ----------------
// BK=64, dbuf-2 (128KB). Per K-tile: 4 stage-units {A-kk0, B-kk0, A-kk1, B-kk1},
// each 16KB = 2 gload16/thread. 4 phases/K-tile, each:
//   {ds_read 4-8 b128 || stage 1 unit} -> barrier -> lgkmcnt(0) -> setprio(1)
//   -> 16 MFMA -> setprio(0) [-> counted vmcnt] -> barrier
// vmcnt(4) TWICE per K-tile (end p1, end p3), never 0 mid-loop:
//   end of T p3: outstanding u0..u3(T+1) [8] -> retire u0,u1(T+1) (needed T+1 p0/p1)
//   end of T p1: outstanding u2,u3(T) + u0,u1(T+1) [8] -> retire u2,u3(T) (needed p2/p3)
// Every unit has >=3 phases issue-to-wait slack. Reads use the verified
// zero-conflict granule-XOR pattern (rounds 3-10: SQ_LDS_BANK_CONFLICT = 0).
__device__ __forceinline__ void gemm256_core(const bf16* __restrict__ Ag,
                                             const bf16* __restrict__ Bg,
                                             char* lds, f32x4 (&acc)[8][4]) {
  const int tid = threadIdx.x;
  const int lane = tid & 63, wid = tid >> 6;
  const int g = lane >> 4, r16 = lane & 15;
  const int wm = wid >> 2, wn = wid & 3;
  const int swz = ((g ^ ((r16 >> 1) & 3)) << 4);

  const int srow = wid * 16 + (lane >> 2);
  const int sg = ((lane & 3) ^ ((lane >> 3) & 3)) * 8;
  const bf16* gA = Ag + (size_t)srow * 2048 + sg;
  const bf16* gB = Bg + (size_t)srow * 2048 + sg;
  const int sdst = wid * 1024;

  const int arow0 = wm * 128 + r16;
  const int brow0 = wn * 64 + r16;

  // LDS map per buffer (64KB): [A-kk0 16K][A-kk1 16K][B-kk0 16K][B-kk1 16K]
#define STAGEU(ab_, kk_, buf_, tt_)                                       \
  {                                                                       \
    const bf16* s_ = ((ab_) ? gB : gA) + (size_t)(tt_) * 64 + (kk_) * 32; \
    char* d_ = lds + (buf_) + (ab_) * 32768 + (kk_) * 16384 + sdst;       \
    gload16(s_, d_);                                                      \
    gload16(s_ + (size_t)128 * 2048, d_ + 8192);                          \
  }

#define RD_B(kk_, buf_)                                                   \
  {                                                                       \
    const char* Bb_ = lds + (buf_) + 32768 + (kk_) * 16384;               \
    _Pragma("unroll") for (int j_ = 0; j_ < 4; ++j_)                      \
      bfr[j_] = *(const bf16x8*)(Bb_ + (brow0 + j_ * 16) * 64 + swz);     \
  }

#define RD_A(kk_, buf_, i0_)                                              \
  {                                                                       \
    const char* Ab_ = lds + (buf_) + (kk_) * 16384;                       \
    _Pragma("unroll") for (int i_ = 0; i_ < 4; ++i_)                      \
      afr[i_] = *(const bf16x8*)(Ab_ + (arow0 + ((i0_) + i_) * 16) * 64 + swz); \
  }

#define MFQ(i0_)                                                          \
  __builtin_amdgcn_s_barrier();                                           \
  asm volatile("s_waitcnt lgkmcnt(0)" ::: "memory");                      \
  __builtin_amdgcn_sched_barrier(0);                                      \
  __builtin_amdgcn_s_setprio(1);                                          \
  _Pragma("unroll") for (int i_ = 0; i_ < 4; ++i_)                        \
  _Pragma("unroll") for (int j_ = 0; j_ < 4; ++j_)                        \
    acc[(i0_) + i_][j_] = MFMA16(afr[i_], bfr[j_], acc[(i0_) + i_][j_]);  \
  __builtin_amdgcn_s_setprio(0);

  bf16x8 afr[4], bfr[4];

  // prologue: stage tile 0 fully (one-time full drain), barrier
  STAGEU(0, 0, 0, 0) STAGEU(1, 0, 0, 0) STAGEU(0, 1, 0, 0) STAGEU(1, 1, 0, 0)
  asm volatile("s_waitcnt vmcnt(0)" ::: "memory");
  __builtin_amdgcn_s_barrier();

  for (int T = 0; T < 32; ++T) {
    const int buf = (T & 1) << 16;
    const int nbf = buf ^ 65536;
    // ---- phase 0: B-kk0 + A-kk0 i0-3 || stage A-kk0(T+1) ----
    RD_B(0, buf) RD_A(0, buf, 0)
    if (T < 31) STAGEU(0, 0, nbf, T + 1)
    MFQ(0)
    __builtin_amdgcn_s_barrier();
    // ---- phase 1: A-kk0 i4-7 || stage B-kk0(T+1); retire u2,u3(T) ----
    RD_A(0, buf, 4)
    if (T < 31) STAGEU(1, 0, nbf, T + 1)
    MFQ(4)
    if (T < 31) { asm volatile("s_waitcnt vmcnt(4)" ::: "memory"); }
    else        { asm volatile("s_waitcnt vmcnt(0)" ::: "memory"); }
    __builtin_amdgcn_s_barrier();
    // ---- phase 2: B-kk1 + A-kk1 i0-3 || stage A-kk1(T+1) ----
    RD_B(1, buf) RD_A(1, buf, 0)
    if (T < 31) STAGEU(0, 1, nbf, T + 1)
    MFQ(0)
    __builtin_amdgcn_s_barrier();
    // ---- phase 3: A-kk1 i4-7 || stage B-kk1(T+1); retire u0,u1(T+1) ----
    RD_A(1, buf, 4)
    if (T < 31) STAGEU(1, 1, nbf, T + 1)
    MFQ(4)
    if (T < 31) { asm volatile("s_waitcnt vmcnt(4)" ::: "memory"); }
    __builtin_amdgcn_s_barrier();
  }
#undef STAGEU
#undef RD_B
#undef RD_A
#undef MFQ
}

// ---------------- QKV projection GEMM (256^2 tile), scatter to tile-major ----------------
// Q pre-scaled by SCALE*log2(e) so attention uses exp2 directly.
__global__ void __launch_bounds__(512, 2) gemm_qkv_kernel(
    const bf16* __restrict__ Xb, const bf16* __restrict__ W0, const bf16* __restrict__ W1,
    const bf16* __restrict__ W2, bf16* __restrict__ q_t, bf16* __restrict__ k_t,
    bf16* __restrict__ v_t) {
  __shared__ char lds[131072];
  int bid = blockIdx.x;
  int xcd = bid & 7, idx = bid >> 3;          // 768 = 8 XCD chunks of 96
  int by = xcd * 4 + idx / 24, bx = idx % 24; // m-major within chunk for L2 reuse
  int which = bx >> 3;
  int m0 = by * 256, n0 = (bx & 7) * 256;
  const bf16* W = which == 0 ? W0 : (which == 1 ? W1 : W2);

  f32x4 acc[8][4] = {};
  gemm256_core(Xb + (size_t)m0 * 2048, W + (size_t)n0 * 2048, lds, acc);

  int lane = threadIdx.x & 63, wid = threadIdx.x >> 6;
  int g = lane >> 4, r16 = lane & 15;
  int wm = wid >> 2, wn = wid & 3;
#pragma unroll
  for (int i = 0; i < 8; ++i) {
#pragma unroll
    for (int r = 0; r < 4; ++r) {
      int m = m0 + wm * 128 + i * 16 + g * 4 + r;
      int b = m >> 12, s = m & 4095;
      int hg = s >> 6, wg = s & 63;
      int t = ((hg >> 3) << 2) + (wg >> 4);
      int tn = ((hg & 7) << 4) + (wg & 15);
#pragma unroll
      for (int j = 0; j < 4; ++j) {
        int n = n0 + wn * 64 + j * 16 + r16;
        int h = n >> 6, hd = n & 63;
        float val = acc[i][j][r];
        size_t base = ((size_t)(b * 32 + h) * 32 + t);
        if (which == 0)
          q_t[(base * 128 + tn) * 64 + hd] = (bf16)(val * 0.18033688056680255f);
        else if (which == 1)
          k_t[(base * 128 + tn) * 64 + hd] = (bf16)val;
        else
          v_t[(base * 64 + hd) * 128 + tn] = (bf16)val;
      }
    }
  }
}

// ---------------- output GEMM: out = o_bf @ Wo, fp32 row-major ----------------
__global__ void __launch_bounds__(512, 2) gemm_out_kernel(const bf16* __restrict__ A,
                                                          const bf16* __restrict__ W,
                                                          float* __restrict__ C) {
  __shared__ char lds[131072];
  int bid = blockIdx.x;
  int xcd = bid & 7, idx = bid >> 3;         // 256 = 8 chunks of 32
  int by = xcd * 4 + idx / 8, bx = idx & 7;
  int m0 = by * 256, n0 = bx * 256;

  f32x4 acc[8][4] = {};
  gemm256_core(A + (size_t)m0 * 2048, W + (size_t)n0 * 2048, lds, acc);

  int lane = threadIdx.x & 63, wid = threadIdx.x >> 6;
  int g = lane >> 4, r16 = lane & 15;
  int wm = wid >> 2, wn = wid & 3;
#pragma unroll
  for (int i = 0; i < 8; ++i)
#pragma unroll
    for (int j = 0; j < 4; ++j)
#pragma unroll
      for (int r = 0; r < 4; ++r) {
        int m = m0 + wm * 128 + i * 16 + g * 4 + r;
        int n = n0 + wn * 64 + j * 16 + r16;
        C[(size_t)m * 2048 + n] = acc[i][j][r];
      }
}

// ---------------- block-sparse tile attention: shift-free softmax (round-8) ----------------
__global__ void __launch_bounds__(256) attn_kernel(const bf16* __restrict__ q_t,
                                                   const bf16* __restrict__ k_t,
                                                   const bf16* __restrict__ v_t,
                                                   bf16* __restrict__ o_bf) {
  __shared__ char Pl[128 * 256];  // P tile, bf16, XOR-swizzled rows of 256B
  int bid = blockIdx.x;
  int bh = (bid & 7) * 8 + (bid >> 8);
  int t = (bid >> 3) & 31;
  int h = bh & 31, b = bh >> 5;
  int tid = threadIdx.x, w = tid >> 6, lane = tid & 63;
  int g = lane >> 4, r16 = lane & 15;

  const size_t qoff = ((size_t)bh * 32 + t) * (128 * 64);
  bf16x8 qf[2][2];
#pragma unroll
  for (int mf = 0; mf < 2; ++mf)
#pragma unroll
    for (int kf = 0; kf < 2; ++kf)
      qf[mf][kf] = *(const bf16x8*)&q_t[qoff + (size_t)(w * 32 + mf * 16 + r16) * 64 + kf * 32 + g * 8];

  bf16x8 ones;
#pragma unroll
  for (int j = 0; j < 8; ++j) ones[j] = (bf16)1.0f;

  f32x4 oacc[2][4] = {};
  f32x4 lacc[2] = {};

  int qh = t >> 2, qw = t & 3;
  int ch = qh < 1 ? 1 : (qh > 7 ? 7 : qh);
  int cw = qw < 1 ? 1 : (qw > 3 ? 3 : qw);

  for (int c = 0; c < 4; ++c) {
    int vt = (ch - 1 + (c >> 1)) * 4 + (cw - 1 + (c & 1));
    const bf16* Kt = k_t + ((size_t)bh * 32 + vt) * (128 * 64);
    const bf16* Vt = v_t + ((size_t)bh * 32 + vt) * (128 * 64);

    f32x4 s[2][8];
#pragma unroll
    for (int nf = 0; nf < 8; ++nf) {
      bf16x8 kf0 = *(const bf16x8*)&Kt[(nf * 16 + r16) * 64 + g * 8];
      bf16x8 kf1 = *(const bf16x8*)&Kt[(nf * 16 + r16) * 64 + 32 + g * 8];
#pragma unroll
      for (int mf = 0; mf < 2; ++mf) {
        f32x4 z = {};
        z = MFMA16(qf[mf][0], kf0, z);
        z = MFMA16(qf[mf][1], kf1, z);
        s[mf][nf] = z;
      }
    }

#pragma unroll
    for (int mf = 0; mf < 2; ++mf)
#pragma unroll
      for (int r = 0; r < 4; ++r) {
        int row = w * 32 + mf * 16 + g * 4 + r;
        int rb = row * 256;
        int swzp = (row & 7) << 4;
#pragma unroll
        for (int nf = 0; nf < 8; ++nf) {
          int addr = (rb + (nf * 16 + r16) * 2) ^ swzp;
          *(bf16*)(Pl + addr) = (bf16)__builtin_amdgcn_exp2f(s[mf][nf][r]);
        }
      }
    __syncthreads();

#pragma unroll
    for (int ks = 0; ks < 4; ++ks) {
      bf16x8 pf[2];
#pragma unroll
      for (int mf = 0; mf < 2; ++mf) {
        int row = w * 32 + mf * 16 + r16;
        int addr = (row * 256 + ks * 64 + g * 16) ^ ((row & 7) << 4);
        pf[mf] = *(const bf16x8*)(Pl + addr);
      }
      bf16x8 vf[4];
#pragma unroll
      for (int hf = 0; hf < 4; ++hf)
        vf[hf] = *(const bf16x8*)&Vt[(hf * 16 + r16) * 128 + ks * 32 + g * 8];
#pragma unroll
      for (int mf = 0; mf < 2; ++mf) {
        lacc[mf] = MFMA16(pf[mf], ones, lacc[mf]);
#pragma unroll
        for (int hf = 0; hf < 4; ++hf)
          oacc[mf][hf] = MFMA16(pf[mf], vf[hf], oacc[mf][hf]);
      }
    }
    __syncthreads();
  }

  int nth = t >> 2, ntw = t & 3;
#pragma unroll
  for (int mf = 0; mf < 2; ++mf)
#pragma unroll
    for (int r = 0; r < 4; ++r) {
      float inv = __builtin_amdgcn_rcpf(lacc[mf][r]);
      int tn = w * 32 + mf * 16 + g * 4 + r;
      int stok = (nth * 8 + (tn >> 4)) * 64 + ntw * 16 + (tn & 15);
#pragma unroll
      for (int hf = 0; hf < 4; ++hf) {
        int col = h * 64 + hf * 16 + r16;
        o_bf[((size_t)b * 4096 + stok) * 2048 + col] = (bf16)(oacc[mf][hf][r] * inv);
      }
    }
}

// ---------------- launcher ----------------
extern "C" void kernel_launch(void* const* d_in, const int* in_sizes, int n_in,
                              void* d_out, int out_size, void* d_ws, size_t ws_size,
                              hipStream_t stream) {
  const float* X = (const float*)d_in[0];
  const float* Wq = (const float*)d_in[1];
  const float* Wk = (const float*)d_in[2];
  const float* Wv = (const float*)d_in[3];
  const float* Wo = (const float*)d_in[4];
  float* out = (float*)d_out;
  char* ws = (char*)d_ws;
  if (ws_size < 159383552u) return;  // need ~159.4 MB scratch

  bf16* Xb  = (bf16*)(ws + 0);           // 33.5 MB, later reused as o_bf
  bf16* WT0 = (bf16*)(ws + 33554432u);   // 8.4 MB (WqT, later WoT)
  bf16* WT1 = (bf16*)(ws + 41943040u);   // WkT
  bf16* WT2 = (bf16*)(ws + 50331648u);   // WvT
  bf16* q_t = (bf16*)(ws + 58720256u);   // 33.5 MB
  bf16* k_t = (bf16*)(ws + 92274688u);   // 33.5 MB
  bf16* v_t = (bf16*)(ws + 125829120u);  // 33.5 MB
  bf16* o_bf = Xb;

  cast_x_kernel<<<16384, 256, 0, stream>>>(X, Xb);
  transpose_w3_kernel<<<3072, 256, 0, stream>>>(Wq, Wk, Wv, WT0, WT1, WT2);
  gemm_qkv_kernel<<<768, 512, 0, stream>>>(Xb, WT0, WT1, WT2, q_t, k_t, v_t);
  attn_kernel<<<2048, 256, 0, stream>>>(q_t, k_t, v_t, o_bf);
  transpose_w_kernel<<<1024, 256, 0, stream>>>(Wo, WT0);
  gemm_out_kernel<<<256, 512, 0, stream>>>(o_bf, WT0, out);
}

// Round 12
// 445.216 us; speedup vs baseline: 1.0346x; 1.0346x over previous
//
#include <hip/hip_runtime.h>

typedef __bf16 bf16;
typedef __attribute__((ext_vector_type(8))) __bf16 bf16x8;
typedef __attribute__((ext_vector_type(4))) __bf16 bf16x4;
typedef __attribute__((ext_vector_type(4))) float f32x4;

#define MFMA16(a, b, c) __builtin_amdgcn_mfma_f32_16x16x32_bf16((a), (b), (c), 0, 0, 0)

__device__ __forceinline__ void gload16(const void* g, void* lds) {
  __builtin_amdgcn_global_load_lds(
      (__attribute__((address_space(1))) unsigned int*)(unsigned long long)g,
      (__attribute__((address_space(3))) unsigned int*)lds, 16, 0, 0);
}

// ---------------- cast X (fp32 -> bf16) ----------------
__global__ void __launch_bounds__(256) cast_x_kernel(const float* __restrict__ X,
                                                     bf16* __restrict__ Xb) {
  int i = (blockIdx.x * 256 + threadIdx.x) * 4;
  f32x4 v = *(const f32x4*)(X + i);
  bf16x4 o;
  o[0] = (bf16)v[0]; o[1] = (bf16)v[1]; o[2] = (bf16)v[2]; o[3] = (bf16)v[3];
  *(bf16x4*)(Xb + i) = o;
}

// ---------------- transpose + cast 3 weights in one launch: WT[n][k] = W[k][n] ----------------
__global__ void __launch_bounds__(256) transpose_w3_kernel(const float* __restrict__ Wq,
                                                           const float* __restrict__ Wk,
                                                           const float* __restrict__ Wv,
                                                           bf16* __restrict__ T0,
                                                           bf16* __restrict__ T1,
                                                           bf16* __restrict__ T2) {
  __shared__ float tile[64][65];
  int which = blockIdx.x >> 10;
  int bid = blockIdx.x & 1023;
  const float* W = which == 0 ? Wq : (which == 1 ? Wk : Wv);
  bf16* WT = which == 0 ? T0 : (which == 1 ? T1 : T2);
  int n0 = (bid & 31) * 64;
  int k0 = (bid >> 5) * 64;
  int tid = threadIdx.x;
  int r = tid >> 4;
  int c4 = (tid & 15) * 4;
#pragma unroll
  for (int i = 0; i < 4; ++i) {
    f32x4 v = *(const f32x4*)(W + (size_t)(k0 + r + i * 16) * 2048 + n0 + c4);
    tile[r + i * 16][c4 + 0] = v[0];
    tile[r + i * 16][c4 + 1] = v[1];
    tile[r + i * 16][c4 + 2] = v[2];
    tile[r + i * 16][c4 + 3] = v[3];
  }
  __syncthreads();
#pragma unroll
  for (int i = 0; i < 4; ++i) {
    int n = r + i * 16;
    bf16x4 o;
    o[0] = (bf16)tile[c4 + 0][n];
    o[1] = (bf16)tile[c4 + 1][n];
    o[2] = (bf16)tile[c4 + 2][n];
    o[3] = (bf16)tile[c4 + 3][n];
    *(bf16x4*)(WT + (size_t)(n0 + n) * 2048 + k0 + c4) = o;
  }
}

__global__ void __launch_bounds__(256) transpose_w_kernel(const float* __restrict__ W,
                                                          bf16* __restrict__ WT) {
  __shared__ float tile[64][65];
  int n0 = (blockIdx.x & 31) * 64;
  int k0 = (blockIdx.x >> 5) * 64;
  int tid = threadIdx.x;
  int r = tid >> 4;
  int c4 = (tid & 15) * 4;
#pragma unroll
  for (int i = 0; i < 4; ++i) {
    f32x4 v = *(const f32x4*)(W + (size_t)(k0 + r + i * 16) * 2048 + n0 + c4);
    tile[r + i * 16][c4 + 0] = v[0];
    tile[r + i * 16][c4 + 1] = v[1];
    tile[r + i * 16][c4 + 2] = v[2];
    tile[r + i * 16][c4 + 3] = v[3];
  }
  __syncthreads();
#pragma unroll
  for (int i = 0; i < 4; ++i) {
    int n = r + i * 16;
    bf16x4 o;
    o[0] = (bf16)tile[c4 + 0][n];
    o[1] = (bf16)tile[c4 + 1][n];
    o[2] = (bf16)tile[c4 + 2][n];
    o[3] = (bf16)tile[c4 + 3][n];
    *(bf16x4*)(WT + (size_t)(n0 + n) * 2048 + k0 + c4) = o;
  }
}

// ---------------- 256x256 GEMM core: ring-4, reg-prefetch across the barrier (round-10) ----
__device__ __forceinline__ void gemm256_core(const bf16* __restrict__ Ag,
                                             const bf16* __restrict__ Bg,
                                             char* lds, f32x4 (&acc)[8][4]) {
  const int tid = threadIdx.x;
  const int lane = tid & 63, wid = tid >> 6;
  const int g = lane >> 4, r16 = lane & 15;
  const int wm = wid >> 2, wn = wid & 3;
  const int swz = ((g ^ ((r16 >> 1) & 3)) << 4);

  const int srow = wid * 32 + (lane >> 2);
  const int scol = ((lane & 3) ^ ((lane >> 3) & 3)) * 8;
  const bf16* gA = Ag + (size_t)srow * 2048 + scol;
  const bf16* gB = Bg + (size_t)srow * 2048 + scol;
  char* sA = lds + wid * 2048;
  char* sB = lds + 16384 + wid * 2048;

  const int arow0 = wm * 128 + r16;
  const int brow0 = wn * 64 + r16;

#define STAGE(bf_, tt_)                                                  \
  {                                                                      \
    char* dA_ = sA + (bf_) * 32768;                                      \
    const bf16* sA_ = gA + (size_t)(tt_) * 32;                           \
    gload16(sA_, dA_);                                                   \
    gload16(sA_ + (size_t)16 * 2048, dA_ + 1024);                        \
    char* dB_ = sB + (bf_) * 32768;                                      \
    const bf16* sB_ = gB + (size_t)(tt_) * 32;                           \
    gload16(sB_, dB_);                                                   \
    gload16(sB_ + (size_t)16 * 2048, dB_ + 1024);                        \
  }

#define READF(fa_, fb_, base_)                                           \
  {                                                                      \
    const char* Ab_ = lds + (base_);                                     \
    const char* Bb_ = Ab_ + 16384;                                       \
    _Pragma("unroll") for (int j_ = 0; j_ < 4; ++j_)                     \
      fb_[j_] = *(const bf16x8*)(Bb_ + (brow0 + j_ * 16) * 64 + swz);    \
    _Pragma("unroll") for (int i_ = 0; i_ < 8; ++i_)                     \
      fa_[i_] = *(const bf16x8*)(Ab_ + (arow0 + i_ * 16) * 64 + swz);    \
  }

#define MF(fa_, fb_)                                                     \
  {                                                                      \
    _Pragma("unroll") for (int i_ = 0; i_ < 8; ++i_)                     \
    _Pragma("unroll") for (int j_ = 0; j_ < 4; ++j_)                     \
      acc[i_][j_] = MFMA16(fa_[i_], fb_[j_], acc[i_][j_]);               \
  }

#define VMCHAIN(u_)                                                      \
  if ((u_) <= 60)      { asm volatile("s_waitcnt vmcnt(4)" ::: "memory"); } \
  else if ((u_) == 61) { asm volatile("s_waitcnt vmcnt(0)" ::: "memory"); }

  bf16x8 fA0[8], fB0[4], fA1[8], fB1[4];

  STAGE(0, 0) STAGE(1, 1) STAGE(2, 2)
  asm volatile("s_waitcnt vmcnt(4)" ::: "memory");
  __builtin_amdgcn_s_barrier();
  READF(fA0, fB0, 0)

  for (int t = 0; t < 64; t += 2) {
    if (t + 3 < 64) STAGE((t + 3) & 3, t + 3)
    VMCHAIN(t)
    READF(fA1, fB1, (size_t)((t + 1) & 3) * 32768)
    __builtin_amdgcn_sched_barrier(0);
    MF(fA0, fB0)
    __builtin_amdgcn_s_barrier();
    __builtin_amdgcn_sched_barrier(0);
    if (t + 4 < 64) STAGE((t + 4) & 3, t + 4)
    VMCHAIN(t + 1)
    READF(fA0, fB0, (size_t)((t + 2) & 3) * 32768)
    __builtin_amdgcn_sched_barrier(0);
    MF(fA1, fB1)
    __builtin_amdgcn_s_barrier();
    __builtin_amdgcn_sched_barrier(0);
  }
#undef STAGE
#undef READF
#undef MF
#undef VMCHAIN
}

// ---------------- QKV projection GEMM (256^2 tile), scatter to tile-major ----------------
// Q pre-scaled by SCALE*log2(e) so attention uses exp2 directly.
__global__ void __launch_bounds__(512, 2) gemm_qkv_kernel(
    const bf16* __restrict__ Xb, const bf16* __restrict__ W0, const bf16* __restrict__ W1,
    const bf16* __restrict__ W2, bf16* __restrict__ q_t, bf16* __restrict__ k_t,
    bf16* __restrict__ v_t) {
  __shared__ char lds[131072];
  int bid = blockIdx.x;
  int xcd = bid & 7, idx = bid >> 3;          // 768 = 8 XCD chunks of 96
  int by = xcd * 4 + idx / 24, bx = idx % 24;
  int which = bx >> 3;
  int m0 = by * 256, n0 = (bx & 7) * 256;
  const bf16* W = which == 0 ? W0 : (which == 1 ? W1 : W2);

  f32x4 acc[8][4] = {};
  gemm256_core(Xb + (size_t)m0 * 2048, W + (size_t)n0 * 2048, lds, acc);

  int lane = threadIdx.x & 63, wid = threadIdx.x >> 6;
  int g = lane >> 4, r16 = lane & 15;
  int wm = wid >> 2, wn = wid & 3;
#pragma unroll
  for (int i = 0; i < 8; ++i) {
#pragma unroll
    for (int r = 0; r < 4; ++r) {
      int m = m0 + wm * 128 + i * 16 + g * 4 + r;
      int b = m >> 12, s = m & 4095;
      int hg = s >> 6, wg = s & 63;
      int t = ((hg >> 3) << 2) + (wg >> 4);
      int tn = ((hg & 7) << 4) + (wg & 15);
#pragma unroll
      for (int j = 0; j < 4; ++j) {
        int n = n0 + wn * 64 + j * 16 + r16;
        int h = n >> 6, hd = n & 63;
        float val = acc[i][j][r];
        size_t base = ((size_t)(b * 32 + h) * 32 + t);
        if (which == 0)
          q_t[(base * 128 + tn) * 64 + hd] = (bf16)(val * 0.18033688056680255f);
        else if (which == 1)
          k_t[(base * 128 + tn) * 64 + hd] = (bf16)val;
        else
          v_t[(base * 64 + hd) * 128 + tn] = (bf16)val;
      }
    }
  }
}

// ---------------- output GEMM: out = o_bf @ Wo, fp32 row-major ----------------
__global__ void __launch_bounds__(512, 2) gemm_out_kernel(const bf16* __restrict__ A,
                                                          const bf16* __restrict__ W,
                                                          float* __restrict__ C) {
  __shared__ char lds[131072];
  int bid = blockIdx.x;
  int xcd = bid & 7, idx = bid >> 3;         // 256 = 8 chunks of 32
  int by = xcd * 4 + idx / 8, bx = idx & 7;
  int m0 = by * 256, n0 = bx * 256;

  f32x4 acc[8][4] = {};
  gemm256_core(A + (size_t)m0 * 2048, W + (size_t)n0 * 2048, lds, acc);

  int lane = threadIdx.x & 63, wid = threadIdx.x >> 6;
  int g = lane >> 4, r16 = lane & 15;
  int wm = wid >> 2, wn = wid & 3;
#pragma unroll
  for (int i = 0; i < 8; ++i)
#pragma unroll
    for (int j = 0; j < 4; ++j)
#pragma unroll
      for (int r = 0; r < 4; ++r) {
        int m = m0 + wm * 128 + i * 16 + g * 4 + r;
        int n = n0 + wn * 64 + j * 16 + r16;
        C[(size_t)m * 2048 + n] = acc[i][j][r];
      }
}

// ---------------- block-sparse tile attention: shift-free softmax, barrier-free ----------------
// KEY: each wave's P slab (rows [w*32, w*32+32)) is written AND read only by
// wave w. The former __syncthreads() pair guarded nothing -> removed. Within-
// wave LDS write->read ordering is program-order via the per-wave in-order DS
// pipe; sched_barrier(0) fences pin program order against compiler motion.
// Waves now free-run: one wave's exp2/VALU overlaps another's MFMA/LDS.
__global__ void __launch_bounds__(256) attn_kernel(const bf16* __restrict__ q_t,
                                                   const bf16* __restrict__ k_t,
                                                   const bf16* __restrict__ v_t,
                                                   bf16* __restrict__ o_bf) {
  __shared__ char Pl[128 * 256];  // 4 wave-private 8KB slabs, XOR-swizzled rows
  int bid = blockIdx.x;
  int bh = (bid & 7) * 8 + (bid >> 8);
  int t = (bid >> 3) & 31;
  int h = bh & 31, b = bh >> 5;
  int tid = threadIdx.x, w = tid >> 6, lane = tid & 63;
  int g = lane >> 4, r16 = lane & 15;

  const size_t qoff = ((size_t)bh * 32 + t) * (128 * 64);
  bf16x8 qf[2][2];
#pragma unroll
  for (int mf = 0; mf < 2; ++mf)
#pragma unroll
    for (int kf = 0; kf < 2; ++kf)
      qf[mf][kf] = *(const bf16x8*)&q_t[qoff + (size_t)(w * 32 + mf * 16 + r16) * 64 + kf * 32 + g * 8];

  bf16x8 ones;
#pragma unroll
  for (int j = 0; j < 8; ++j) ones[j] = (bf16)1.0f;

  f32x4 oacc[2][4] = {};
  f32x4 lacc[2] = {};

  int qh = t >> 2, qw = t & 3;
  int ch = qh < 1 ? 1 : (qh > 7 ? 7 : qh);
  int cw = qw < 1 ? 1 : (qw > 3 ? 3 : qw);

  for (int c = 0; c < 4; ++c) {
    int vt = (ch - 1 + (c >> 1)) * 4 + (cw - 1 + (c & 1));
    const bf16* Kt = k_t + ((size_t)bh * 32 + vt) * (128 * 64);
    const bf16* Vt = v_t + ((size_t)bh * 32 + vt) * (128 * 64);

    f32x4 s[2][8];
#pragma unroll
    for (int nf = 0; nf < 8; ++nf) {
      bf16x8 kf0 = *(const bf16x8*)&Kt[(nf * 16 + r16) * 64 + g * 8];
      bf16x8 kf1 = *(const bf16x8*)&Kt[(nf * 16 + r16) * 64 + 32 + g * 8];
#pragma unroll
      for (int mf = 0; mf < 2; ++mf) {
        f32x4 z = {};
        z = MFMA16(qf[mf][0], kf0, z);
        z = MFMA16(qf[mf][1], kf1, z);
        s[mf][nf] = z;
      }
    }

    // P = exp2(S') -> bf16 -> wave-private swizzled LDS slab (no barrier).
#pragma unroll
    for (int mf = 0; mf < 2; ++mf)
#pragma unroll
      for (int r = 0; r < 4; ++r) {
        int row = w * 32 + mf * 16 + g * 4 + r;
        int rb = row * 256;
        int swzp = (row & 7) << 4;
#pragma unroll
        for (int nf = 0; nf < 8; ++nf) {
          int addr = (rb + (nf * 16 + r16) * 2) ^ swzp;
          *(bf16*)(Pl + addr) = (bf16)__builtin_amdgcn_exp2f(s[mf][nf][r]);
        }
      }
    __builtin_amdgcn_sched_barrier(0);  // pin store->load program order

    // O += P @ V ; l += P @ 1 (reads only this wave's slab)
#pragma unroll
    for (int ks = 0; ks < 4; ++ks) {
      bf16x8 pf[2];
#pragma unroll
      for (int mf = 0; mf < 2; ++mf) {
        int row = w * 32 + mf * 16 + r16;
        int addr = (row * 256 + ks * 64 + g * 16) ^ ((row & 7) << 4);
        pf[mf] = *(const bf16x8*)(Pl + addr);
      }
      bf16x8 vf[4];
#pragma unroll
      for (int hf = 0; hf < 4; ++hf)
        vf[hf] = *(const bf16x8*)&Vt[(hf * 16 + r16) * 128 + ks * 32 + g * 8];
#pragma unroll
      for (int mf = 0; mf < 2; ++mf) {
        lacc[mf] = MFMA16(pf[mf], ones, lacc[mf]);
#pragma unroll
        for (int hf = 0; hf < 4; ++hf)
          oacc[mf][hf] = MFMA16(pf[mf], vf[hf], oacc[mf][hf]);
      }
    }
    __builtin_amdgcn_sched_barrier(0);  // pin load->next-tile-store order
  }

  int nth = t >> 2, ntw = t & 3;
#pragma unroll
  for (int mf = 0; mf < 2; ++mf)
#pragma unroll
    for (int r = 0; r < 4; ++r) {
      float inv = __builtin_amdgcn_rcpf(lacc[mf][r]);
      int tn = w * 32 + mf * 16 + g * 4 + r;
      int stok = (nth * 8 + (tn >> 4)) * 64 + ntw * 16 + (tn & 15);
#pragma unroll
      for (int hf = 0; hf < 4; ++hf) {
        int col = h * 64 + hf * 16 + r16;
        o_bf[((size_t)b * 4096 + stok) * 2048 + col] = (bf16)(oacc[mf][hf][r] * inv);
      }
    }
}

// ---------------- launcher ----------------
extern "C" void kernel_launch(void* const* d_in, const int* in_sizes, int n_in,
                              void* d_out, int out_size, void* d_ws, size_t ws_size,
                              hipStream_t stream) {
  const float* X = (const float*)d_in[0];
  const float* Wq = (const float*)d_in[1];
  const float* Wk = (const float*)d_in[2];
  const float* Wv = (const float*)d_in[3];
  const float* Wo = (const float*)d_in[4];
  float* out = (float*)d_out;
  char* ws = (char*)d_ws;
  if (ws_size < 159383552u) return;  // need ~159.4 MB scratch

  bf16* Xb  = (bf16*)(ws + 0);           // 33.5 MB, later reused as o_bf
  bf16* WT0 = (bf16*)(ws + 33554432u);   // 8.4 MB (WqT, later WoT)
  bf16* WT1 = (bf16*)(ws + 41943040u);   // WkT
  bf16* WT2 = (bf16*)(ws + 50331648u);   // WvT
  bf16* q_t = (bf16*)(ws + 58720256u);   // 33.5 MB
  bf16* k_t = (bf16*)(ws + 92274688u);   // 33.5 MB
  bf16* v_t = (bf16*)(ws + 125829120u);  // 33.5 MB
  bf16* o_bf = Xb;

  cast_x_kernel<<<16384, 256, 0, stream>>>(X, Xb);
  transpose_w3_kernel<<<3072, 256, 0, stream>>>(Wq, Wk, Wv, WT0, WT1, WT2);
  gemm_qkv_kernel<<<768, 512, 0, stream>>>(Xb, WT0, WT1, WT2, q_t, k_t, v_t);
  attn_kernel<<<2048, 256, 0, stream>>>(q_t, k_t, v_t, o_bf);
  transpose_w_kernel<<<1024, 256, 0, stream>>>(Wo, WT0);
  gemm_out_kernel<<<256, 512, 0, stream>>>(o_bf, WT0, out);
}

// Round 13
// 436.581 us; speedup vs baseline: 1.0550x; 1.0198x over previous
//
#include <hip/hip_runtime.h>

typedef __bf16 bf16;
typedef __attribute__((ext_vector_type(8))) __bf16 bf16x8;
typedef __attribute__((ext_vector_type(4))) __bf16 bf16x4;
typedef __attribute__((ext_vector_type(4))) float f32x4;

#define MFMA16(a, b, c) __builtin_amdgcn_mfma_f32_16x16x32_bf16((a), (b), (c), 0, 0, 0)

__device__ __forceinline__ void gload16(const void* g, void* lds) {
  __builtin_amdgcn_global_load_lds(
      (__attribute__((address_space(1))) unsigned int*)(unsigned long long)g,
      (__attribute__((address_space(3))) unsigned int*)lds, 16, 0, 0);
}

// ---------------- shared transpose body: WT[n][k] = W[k][n] for one 64x64 tile ----------------
__device__ __forceinline__ void transpose_tile(const float* __restrict__ W,
                                               bf16* __restrict__ WT, int bid,
                                               float (*tile)[65]) {
  int n0 = (bid & 31) * 64;
  int k0 = (bid >> 5) * 64;
  int tid = threadIdx.x;
  int r = tid >> 4;
  int c4 = (tid & 15) * 4;
#pragma unroll
  for (int i = 0; i < 4; ++i) {
    f32x4 v = *(const f32x4*)(W + (size_t)(k0 + r + i * 16) * 2048 + n0 + c4);
    tile[r + i * 16][c4 + 0] = v[0];
    tile[r + i * 16][c4 + 1] = v[1];
    tile[r + i * 16][c4 + 2] = v[2];
    tile[r + i * 16][c4 + 3] = v[3];
  }
  __syncthreads();
#pragma unroll
  for (int i = 0; i < 4; ++i) {
    int n = r + i * 16;
    bf16x4 o;
    o[0] = (bf16)tile[c4 + 0][n];
    o[1] = (bf16)tile[c4 + 1][n];
    o[2] = (bf16)tile[c4 + 2][n];
    o[3] = (bf16)tile[c4 + 3][n];
    *(bf16x4*)(WT + (size_t)(n0 + n) * 2048 + k0 + c4) = o;
  }
}

// ---------------- prep: 3 weight transposes + X cast in ONE launch ----------------
// blocks [0,3072): transpose Wq/Wk/Wv (1024 tiles each).
// blocks [3072,11264): cast X fp32->bf16, 8 elems/thread (8192 blocks).
__global__ void __launch_bounds__(256) prep_kernel(const float* __restrict__ X,
                                                   const float* __restrict__ Wq,
                                                   const float* __restrict__ Wk,
                                                   const float* __restrict__ Wv,
                                                   bf16* __restrict__ Xb,
                                                   bf16* __restrict__ T0,
                                                   bf16* __restrict__ T1,
                                                   bf16* __restrict__ T2) {
  __shared__ float tile[64][65];
  int bid = blockIdx.x;
  if (bid < 3072) {
    int which = bid >> 10;
    const float* W = which == 0 ? Wq : (which == 1 ? Wk : Wv);
    bf16* WT = which == 0 ? T0 : (which == 1 ? T1 : T2);
    transpose_tile(W, WT, bid & 1023, tile);
  } else {
    size_t i = ((size_t)(bid - 3072) * 256 + threadIdx.x) * 8;
    f32x4 v0 = *(const f32x4*)(X + i);
    f32x4 v1 = *(const f32x4*)(X + i + 4);
    bf16x8 o;
    o[0] = (bf16)v0[0]; o[1] = (bf16)v0[1]; o[2] = (bf16)v0[2]; o[3] = (bf16)v0[3];
    o[4] = (bf16)v1[0]; o[5] = (bf16)v1[1]; o[6] = (bf16)v1[2]; o[7] = (bf16)v1[3];
    *(bf16x8*)(Xb + i) = o;
  }
}

// ---------------- 256x256 GEMM core: ring-4, reg-prefetch across the barrier (round-10) ----
__device__ __forceinline__ void gemm256_core(const bf16* __restrict__ Ag,
                                             const bf16* __restrict__ Bg,
                                             char* lds, f32x4 (&acc)[8][4]) {
  const int tid = threadIdx.x;
  const int lane = tid & 63, wid = tid >> 6;
  const int g = lane >> 4, r16 = lane & 15;
  const int wm = wid >> 2, wn = wid & 3;
  const int swz = ((g ^ ((r16 >> 1) & 3)) << 4);

  const int srow = wid * 32 + (lane >> 2);
  const int scol = ((lane & 3) ^ ((lane >> 3) & 3)) * 8;
  const bf16* gA = Ag + (size_t)srow * 2048 + scol;
  const bf16* gB = Bg + (size_t)srow * 2048 + scol;
  char* sA = lds + wid * 2048;
  char* sB = lds + 16384 + wid * 2048;

  const int arow0 = wm * 128 + r16;
  const int brow0 = wn * 64 + r16;

#define STAGE(bf_, tt_)                                                  \
  {                                                                      \
    char* dA_ = sA + (bf_) * 32768;                                      \
    const bf16* sA_ = gA + (size_t)(tt_) * 32;                           \
    gload16(sA_, dA_);                                                   \
    gload16(sA_ + (size_t)16 * 2048, dA_ + 1024);                        \
    char* dB_ = sB + (bf_) * 32768;                                      \
    const bf16* sB_ = gB + (size_t)(tt_) * 32;                           \
    gload16(sB_, dB_);                                                   \
    gload16(sB_ + (size_t)16 * 2048, dB_ + 1024);                        \
  }

#define READF(fa_, fb_, base_)                                           \
  {                                                                      \
    const char* Ab_ = lds + (base_);                                     \
    const char* Bb_ = Ab_ + 16384;                                       \
    _Pragma("unroll") for (int j_ = 0; j_ < 4; ++j_)                     \
      fb_[j_] = *(const bf16x8*)(Bb_ + (brow0 + j_ * 16) * 64 + swz);    \
    _Pragma("unroll") for (int i_ = 0; i_ < 8; ++i_)                     \
      fa_[i_] = *(const bf16x8*)(Ab_ + (arow0 + i_ * 16) * 64 + swz);    \
  }

#define MF(fa_, fb_)                                                     \
  {                                                                      \
    _Pragma("unroll") for (int i_ = 0; i_ < 8; ++i_)                     \
    _Pragma("unroll") for (int j_ = 0; j_ < 4; ++j_)                     \
      acc[i_][j_] = MFMA16(fa_[i_], fb_[j_], acc[i_][j_]);               \
  }

#define VMCHAIN(u_)                                                      \
  if ((u_) <= 60)      { asm volatile("s_waitcnt vmcnt(4)" ::: "memory"); } \
  else if ((u_) == 61) { asm volatile("s_waitcnt vmcnt(0)" ::: "memory"); }

  bf16x8 fA0[8], fB0[4], fA1[8], fB1[4];

  STAGE(0, 0) STAGE(1, 1) STAGE(2, 2)
  asm volatile("s_waitcnt vmcnt(4)" ::: "memory");
  __builtin_amdgcn_s_barrier();
  READF(fA0, fB0, 0)

  for (int t = 0; t < 64; t += 2) {
    if (t + 3 < 64) STAGE((t + 3) & 3, t + 3)
    VMCHAIN(t)
    READF(fA1, fB1, (size_t)((t + 1) & 3) * 32768)
    __builtin_amdgcn_sched_barrier(0);
    MF(fA0, fB0)
    __builtin_amdgcn_s_barrier();
    __builtin_amdgcn_sched_barrier(0);
    if (t + 4 < 64) STAGE((t + 4) & 3, t + 4)
    VMCHAIN(t + 1)
    READF(fA0, fB0, (size_t)((t + 2) & 3) * 32768)
    __builtin_amdgcn_sched_barrier(0);
    MF(fA1, fB1)
    __builtin_amdgcn_s_barrier();
    __builtin_amdgcn_sched_barrier(0);
  }
#undef STAGE
#undef READF
#undef MF
#undef VMCHAIN
}

// ---------------- QKV projection GEMM (256^2 tile), scatter to tile-major ----------------
// Q pre-scaled by SCALE*log2(e) so attention uses exp2 directly.
__global__ void __launch_bounds__(512, 2) gemm_qkv_kernel(
    const bf16* __restrict__ Xb, const bf16* __restrict__ W0, const bf16* __restrict__ W1,
    const bf16* __restrict__ W2, bf16* __restrict__ q_t, bf16* __restrict__ k_t,
    bf16* __restrict__ v_t) {
  __shared__ char lds[131072];
  int bid = blockIdx.x;
  int xcd = bid & 7, idx = bid >> 3;          // 768 = 8 XCD chunks of 96
  int by = xcd * 4 + idx / 24, bx = idx % 24;
  int which = bx >> 3;
  int m0 = by * 256, n0 = (bx & 7) * 256;
  const bf16* W = which == 0 ? W0 : (which == 1 ? W1 : W2);

  f32x4 acc[8][4] = {};
  gemm256_core(Xb + (size_t)m0 * 2048, W + (size_t)n0 * 2048, lds, acc);

  int lane = threadIdx.x & 63, wid = threadIdx.x >> 6;
  int g = lane >> 4, r16 = lane & 15;
  int wm = wid >> 2, wn = wid & 3;
#pragma unroll
  for (int i = 0; i < 8; ++i) {
#pragma unroll
    for (int r = 0; r < 4; ++r) {
      int m = m0 + wm * 128 + i * 16 + g * 4 + r;
      int b = m >> 12, s = m & 4095;
      int hg = s >> 6, wg = s & 63;
      int t = ((hg >> 3) << 2) + (wg >> 4);
      int tn = ((hg & 7) << 4) + (wg & 15);
#pragma unroll
      for (int j = 0; j < 4; ++j) {
        int n = n0 + wn * 64 + j * 16 + r16;
        int h = n >> 6, hd = n & 63;
        float val = acc[i][j][r];
        size_t base = ((size_t)(b * 32 + h) * 32 + t);
        if (which == 0)
          q_t[(base * 128 + tn) * 64 + hd] = (bf16)(val * 0.18033688056680255f);
        else if (which == 1)
          k_t[(base * 128 + tn) * 64 + hd] = (bf16)val;
        else
          v_t[(base * 64 + hd) * 128 + tn] = (bf16)val;
      }
    }
  }
}

// ---------------- output GEMM: out = o_bf @ Wo, fp32 row-major ----------------
__global__ void __launch_bounds__(512, 2) gemm_out_kernel(const bf16* __restrict__ A,
                                                          const bf16* __restrict__ W,
                                                          float* __restrict__ C) {
  __shared__ char lds[131072];
  int bid = blockIdx.x;
  int xcd = bid & 7, idx = bid >> 3;         // 256 = 8 chunks of 32
  int by = xcd * 4 + idx / 8, bx = idx & 7;
  int m0 = by * 256, n0 = bx * 256;

  f32x4 acc[8][4] = {};
  gemm256_core(A + (size_t)m0 * 2048, W + (size_t)n0 * 2048, lds, acc);

  int lane = threadIdx.x & 63, wid = threadIdx.x >> 6;
  int g = lane >> 4, r16 = lane & 15;
  int wm = wid >> 2, wn = wid & 3;
#pragma unroll
  for (int i = 0; i < 8; ++i)
#pragma unroll
    for (int j = 0; j < 4; ++j)
#pragma unroll
      for (int r = 0; r < 4; ++r) {
        int m = m0 + wm * 128 + i * 16 + g * 4 + r;
        int n = n0 + wn * 64 + j * 16 + r16;
        C[(size_t)m * 2048 + n] = acc[i][j][r];
      }
}

// ---------------- attn (barrier-free, shift-free softmax) + fused Wo transpose ----------------
// blocks [0,2048): attention. blocks [2048,3072): transpose Wo -> WoT (legal here:
// WoT/WT0 is dead after gemm_qkv; gemm_out runs after this kernel). The transpose's
// float tile aliases the attn P-slab LDS.
__global__ void __launch_bounds__(256) attn_kernel(const bf16* __restrict__ q_t,
                                                   const bf16* __restrict__ k_t,
                                                   const bf16* __restrict__ v_t,
                                                   bf16* __restrict__ o_bf,
                                                   const float* __restrict__ Wo,
                                                   bf16* __restrict__ WoT) {
  __shared__ char Pl[128 * 256];  // 4 wave-private 8KB slabs, XOR-swizzled rows
  int bid = blockIdx.x;
  if (bid >= 2048) {
    transpose_tile(Wo, WoT, bid - 2048, (float(*)[65])Pl);
    return;
  }
  int bh = (bid & 7) * 8 + (bid >> 8);
  int t = (bid >> 3) & 31;
  int h = bh & 31, b = bh >> 5;
  int tid = threadIdx.x, w = tid >> 6, lane = tid & 63;
  int g = lane >> 4, r16 = lane & 15;

  const size_t qoff = ((size_t)bh * 32 + t) * (128 * 64);
  bf16x8 qf[2][2];
#pragma unroll
  for (int mf = 0; mf < 2; ++mf)
#pragma unroll
    for (int kf = 0; kf < 2; ++kf)
      qf[mf][kf] = *(const bf16x8*)&q_t[qoff + (size_t)(w * 32 + mf * 16 + r16) * 64 + kf * 32 + g * 8];

  bf16x8 ones;
#pragma unroll
  for (int j = 0; j < 8; ++j) ones[j] = (bf16)1.0f;

  f32x4 oacc[2][4] = {};
  f32x4 lacc[2] = {};

  int qh = t >> 2, qw = t & 3;
  int ch = qh < 1 ? 1 : (qh > 7 ? 7 : qh);
  int cw = qw < 1 ? 1 : (qw > 3 ? 3 : qw);

  for (int c = 0; c < 4; ++c) {
    int vt = (ch - 1 + (c >> 1)) * 4 + (cw - 1 + (c & 1));
    const bf16* Kt = k_t + ((size_t)bh * 32 + vt) * (128 * 64);
    const bf16* Vt = v_t + ((size_t)bh * 32 + vt) * (128 * 64);

    f32x4 s[2][8];
#pragma unroll
    for (int nf = 0; nf < 8; ++nf) {
      bf16x8 kf0 = *(const bf16x8*)&Kt[(nf * 16 + r16) * 64 + g * 8];
      bf16x8 kf1 = *(const bf16x8*)&Kt[(nf * 16 + r16) * 64 + 32 + g * 8];
#pragma unroll
      for (int mf = 0; mf < 2; ++mf) {
        f32x4 z = {};
        z = MFMA16(qf[mf][0], kf0, z);
        z = MFMA16(qf[mf][1], kf1, z);
        s[mf][nf] = z;
      }
    }

    // P = exp2(S') -> bf16 -> wave-private swizzled LDS slab (no barrier).
#pragma unroll
    for (int mf = 0; mf < 2; ++mf)
#pragma unroll
      for (int r = 0; r < 4; ++r) {
        int row = w * 32 + mf * 16 + g * 4 + r;
        int rb = row * 256;
        int swzp = (row & 7) << 4;
#pragma unroll
        for (int nf = 0; nf < 8; ++nf) {
          int addr = (rb + (nf * 16 + r16) * 2) ^ swzp;
          *(bf16*)(Pl + addr) = (bf16)__builtin_amdgcn_exp2f(s[mf][nf][r]);
        }
      }
    __builtin_amdgcn_sched_barrier(0);  // pin store->load program order

    // O += P @ V ; l += P @ 1 (reads only this wave's slab)
#pragma unroll
    for (int ks = 0; ks < 4; ++ks) {
      bf16x8 pf[2];
#pragma unroll
      for (int mf = 0; mf < 2; ++mf) {
        int row = w * 32 + mf * 16 + r16;
        int addr = (row * 256 + ks * 64 + g * 16) ^ ((row & 7) << 4);
        pf[mf] = *(const bf16x8*)(Pl + addr);
      }
      bf16x8 vf[4];
#pragma unroll
      for (int hf = 0; hf < 4; ++hf)
        vf[hf] = *(const bf16x8*)&Vt[(hf * 16 + r16) * 128 + ks * 32 + g * 8];
#pragma unroll
      for (int mf = 0; mf < 2; ++mf) {
        lacc[mf] = MFMA16(pf[mf], ones, lacc[mf]);
#pragma unroll
        for (int hf = 0; hf < 4; ++hf)
          oacc[mf][hf] = MFMA16(pf[mf], vf[hf], oacc[mf][hf]);
      }
    }
    __builtin_amdgcn_sched_barrier(0);  // pin load->next-tile-store order
  }

  int nth = t >> 2, ntw = t & 3;
#pragma unroll
  for (int mf = 0; mf < 2; ++mf)
#pragma unroll
    for (int r = 0; r < 4; ++r) {
      float inv = __builtin_amdgcn_rcpf(lacc[mf][r]);
      int tn = w * 32 + mf * 16 + g * 4 + r;
      int stok = (nth * 8 + (tn >> 4)) * 64 + ntw * 16 + (tn & 15);
#pragma unroll
      for (int hf = 0; hf < 4; ++hf) {
        int col = h * 64 + hf * 16 + r16;
        o_bf[((size_t)b * 4096 + stok) * 2048 + col] = (bf16)(oacc[mf][hf][r] * inv);
      }
    }
}

// ---------------- launcher (4 kernels) ----------------
extern "C" void kernel_launch(void* const* d_in, const int* in_sizes, int n_in,
                              void* d_out, int out_size, void* d_ws, size_t ws_size,
                              hipStream_t stream) {
  const float* X = (const float*)d_in[0];
  const float* Wq = (const float*)d_in[1];
  const float* Wk = (const float*)d_in[2];
  const float* Wv = (const float*)d_in[3];
  const float* Wo = (const float*)d_in[4];
  float* out = (float*)d_out;
  char* ws = (char*)d_ws;
  if (ws_size < 159383552u) return;  // need ~159.4 MB scratch

  bf16* Xb  = (bf16*)(ws + 0);           // 33.5 MB, later reused as o_bf
  bf16* WT0 = (bf16*)(ws + 33554432u);   // 8.4 MB (WqT, later WoT)
  bf16* WT1 = (bf16*)(ws + 41943040u);   // WkT
  bf16* WT2 = (bf16*)(ws + 50331648u);   // WvT
  bf16* q_t = (bf16*)(ws + 58720256u);   // 33.5 MB
  bf16* k_t = (bf16*)(ws + 92274688u);   // 33.5 MB
  bf16* v_t = (bf16*)(ws + 125829120u);  // 33.5 MB
  bf16* o_bf = Xb;

  prep_kernel<<<11264, 256, 0, stream>>>(X, Wq, Wk, Wv, Xb, WT0, WT1, WT2);
  gemm_qkv_kernel<<<768, 512, 0, stream>>>(Xb, WT0, WT1, WT2, q_t, k_t, v_t);
  attn_kernel<<<3072, 256, 0, stream>>>(q_t, k_t, v_t, o_bf, Wo, WT0);
  gemm_out_kernel<<<256, 512, 0, stream>>>(o_bf, WT0, out);
}